// Round 3
// baseline (1010.605 us; speedup 1.0000x reference)
//
#include <hip/hip_runtime.h>
#include <math.h>

typedef unsigned int u32;

// workspace layout (bytes): tiny on purpose this round
#define Z_OFF    0u        // 128*64 f32 pooled sums (32 KB)
#define CNT_OFF  32768u    // 4 u32
#define PSUM_OFF 32832u    // 4 f32

__device__ inline float geluf(float x){ return 0.5f*x*(1.0f+erff(x*0.70710678118654752f)); }

// ---- zero the accumulators (ws is 0xAA-poisoned before every call) ----
__global__ __launch_bounds__(256) void kInit(float* z, u32* cnt, float* psum){
  int i = blockIdx.x*256 + threadIdx.x;
  if (i < 8192) z[i] = 0.f;
  if (i < 4){ cnt[i] = 0u; psum[i] = 0.f; }
}

// ---- fully fused per-token pipeline: patch encoder -> gate -> expert MLP ->
//      atomic pooled sum. One wave per token, 4 tokens per 256-thread block. ----
__global__ __launch_bounds__(256) void kFused(
    const float* __restrict__ x,
    const float* __restrict__ w1, const float* __restrict__ b1,
    const float* __restrict__ w2, const float* __restrict__ b2,
    const float* __restrict__ gw, const float* __restrict__ gb,
    const float* __restrict__ e1, const float* __restrict__ eb1,
    const float* __restrict__ e2, const float* __restrict__ eb2,
    float* __restrict__ z, u32* __restrict__ cnt, float* __restrict__ psum)
{
  __shared__ float xs[4][192];
  __shared__ float h1s[4][64];
  __shared__ float hs[4][64];
  __shared__ float hid[4][256];
  __shared__ float lg[4][4];
  __shared__ int   be_s[4];
  __shared__ float gv_s[4];
  __shared__ float lgp[4];
  __shared__ u32   lgc[4];
  const int tid  = threadIdx.x;
  const int w    = tid >> 6, lane = tid & 63;
  const int tok  = blockIdx.x*4 + w;
  if (tid < 4){ lgp[tid] = 0.f; lgc[tid] = 0u; }

  // stage x row (192 floats) into LDS, coalesced
  for (int r = 0; r < 3; ++r)
    xs[w][lane + 64*r] = x[(size_t)tok*192 + lane + 64*r];
  __syncthreads();

  // patch encoder layer 1: h1[lane] = gelu(b1 + sum_k x[k]*w1[k][lane])
  float a = b1[lane];
  for (int k = 0; k < 192; ++k) a += xs[w][k]*w1[k*64 + lane];
  h1s[w][lane] = geluf(a);
  __syncthreads();

  // patch encoder layer 2 (keep fp32 h for the gate, like the reference)
  float h = b2[lane];
  for (int k = 0; k < 64; ++k) h += h1s[w][k]*w2[k*64 + lane];
  hs[w][lane] = h;
  __syncthreads();

  // gate logits (4 per token)
  if (lane < 4){
    float l = gb[lane];
    for (int k = 0; k < 64; ++k) l += hs[w][k]*gw[k*4 + lane];
    lg[w][lane] = l;
  }
  __syncthreads();

  // softmax + top-1 routing + aux-loss statistics
  if (lane == 0){
    float l0=lg[w][0], l1=lg[w][1], l2=lg[w][2], l3=lg[w][3];
    float mx = fmaxf(fmaxf(l0,l1),fmaxf(l2,l3));
    float x0=expf(l0-mx), x1=expf(l1-mx), x2=expf(l2-mx), x3=expf(l3-mx);
    float inv = 1.f/(x0+x1+x2+x3);
    float p0=x0*inv, p1=x1*inv, p2=x2*inv, p3=x3*inv;
    int be=0; float bv=l0;
    if (l1>bv){bv=l1;be=1;}
    if (l2>bv){bv=l2;be=2;}
    if (l3>bv){bv=l3;be=3;}
    be_s[w]=be;
    gv_s[w]=(be==0)?p0:(be==1)?p1:(be==2)?p2:p3;
    atomicAdd(&lgp[0],p0); atomicAdd(&lgp[1],p1);
    atomicAdd(&lgp[2],p2); atomicAdd(&lgp[3],p3);
    atomicAdd(&lgc[be],1u);
  }
  __syncthreads();

  // this token's expert MLP: D=64 -> HID=256 -> D=64
  const int e    = be_s[w];
  const float gv = gv_s[w];
  const float* W1 = e1 + e*16384;   // [64][256]
  const float* W2 = e2 + e*16384;   // [256][64]
  for (int q = 0; q < 4; ++q){
    int j = q*64 + lane;
    float s = eb1[e*256 + j];
    for (int k = 0; k < 64; ++k) s += hs[w][k]*W1[k*256 + j];
    hid[w][j] = geluf(s);
  }
  __syncthreads();
  float o = eb2[e*64 + lane];
  for (int j = 0; j < 256; ++j) o += hid[w][j]*W2[j*64 + lane];

  // pooled sum over sequence via device atomics (order-nondeterministic, fp32 ok)
  int b = tok >> 10;                // tok = batch*1024 + s
  atomicAdd(&z[b*64 + lane], o*gv);
  __syncthreads();
  if (tid < 4){ atomicAdd(&cnt[tid], lgc[tid]); atomicAdd(&psum[tid], lgp[tid]); }
}

// ---- mean pool finalize + LayerNorm + classifier; block 0 also writes aux ----
__global__ __launch_bounds__(64) void kFinal(
    const float* __restrict__ z, const u32* __restrict__ cnt, const float* __restrict__ psum,
    const float* __restrict__ ln_g, const float* __restrict__ ln_b,
    const float* __restrict__ cw1, const float* __restrict__ cb1,
    const float* __restrict__ cw2, const float* __restrict__ cb2,
    float* __restrict__ out)
{
  __shared__ float z_l[64], zn_l[64], c1_l[64], red[2];
  int tid = threadIdx.x, b = blockIdx.x;
  z_l[tid] = z[b*64 + tid] * (1.0f/1024.0f);
  __syncthreads();
  if (tid == 0){
    float mu = 0.f; for (int i=0;i<64;++i) mu += z_l[i]; mu *= (1.f/64.f);
    float vv = 0.f; for (int i=0;i<64;++i){ float d=z_l[i]-mu; vv += d*d; } vv *= (1.f/64.f);
    red[0]=mu; red[1]=1.0f/sqrtf(vv+1e-5f);
  }
  __syncthreads();
  zn_l[tid] = (z_l[tid]-red[0])*red[1]*ln_g[tid] + ln_b[tid];
  __syncthreads();
  float a1 = cb1[tid];
  for (int k=0;k<64;++k) a1 += zn_l[k]*cw1[k*64+tid];
  c1_l[tid] = geluf(a1);
  __syncthreads();
  if (tid < 10){
    float y = cb2[tid];
    for (int k=0;k<64;++k) y += c1_l[k]*cw2[k*10+tid];
    out[b*10+tid] = y;
  }
  if (b == 0 && tid == 0){
    float aux = 0.f;
    for (int e=0;e<4;++e) aux += (float)cnt[e]*psum[e];
    out[1280] = 4.0f*aux/(131072.0f*131072.0f);
  }
}

// ======================================================================================
extern "C" void kernel_launch(void* const* d_in, const int* in_sizes, int n_in,
                              void* d_out, int out_size, void* d_ws, size_t ws_size,
                              hipStream_t stream)
{
  const float* x    = (const float*)d_in[0];
  const float* pw1  = (const float*)d_in[1];
  const float* pb1  = (const float*)d_in[2];
  const float* pw2  = (const float*)d_in[3];
  const float* pb2  = (const float*)d_in[4];
  const float* gw   = (const float*)d_in[5];
  const float* gb   = (const float*)d_in[6];
  const float* ew1  = (const float*)d_in[7];
  const float* eb1  = (const float*)d_in[8];
  const float* ew2  = (const float*)d_in[9];
  const float* eb2  = (const float*)d_in[10];
  const float* lng  = (const float*)d_in[11];
  const float* lnb  = (const float*)d_in[12];
  const float* cw1  = (const float*)d_in[13];
  const float* cb1  = (const float*)d_in[14];
  const float* cw2  = (const float*)d_in[15];
  const float* cb2  = (const float*)d_in[16];

  char* ws   = (char*)d_ws;
  float* z    = (float*)(ws + Z_OFF);
  u32*   cnt  = (u32*)(ws + CNT_OFF);
  float* psum = (float*)(ws + PSUM_OFF);
  float* out  = (float*)d_out;

  kInit <<<32,    256, 0, stream>>>(z, cnt, psum);
  kFused<<<32768, 256, 0, stream>>>(x, pw1, pb1, pw2, pb2, gw, gb,
                                    ew1, eb1, ew2, eb2, z, cnt, psum);
  kFinal<<<128,   64,  0, stream>>>(z, cnt, psum, lng, lnb, cw1, cb1, cw2, cb2, out);
}

// Round 4
// 392.888 us; speedup vs baseline: 2.5722x; 2.5722x over previous
//
#include <hip/hip_runtime.h>
#include <math.h>

typedef unsigned int  u32;
typedef unsigned short u16;

using bf16x8  = __attribute__((ext_vector_type(8))) __bf16;
using float4v = __attribute__((ext_vector_type(4))) float;

#define MFMA16(a,b,c) __builtin_amdgcn_mfma_f32_16x16x32_bf16(a,b,c,0,0,0)

// ---- fast-path workspace layout (bytes) — total 338 KB ----
#define W1P_OFF   0u          // 12288 u16
#define W2P_OFF   24576u      // 4096 u16
#define GWP_OFF   40960u      // 1024 u16 (gate padded to m=16)
#define E1P_OFF   43008u      // 65536 u16 (4 experts x 16384)
#define E2P_OFF   174080u     // 65536 u16 (4 experts x 16384)
#define ZF_OFF    305152u     // 8192 f32
#define CNTF_OFF  337920u     // 4 u32
#define PSUMF_OFF 337984u     // 4 f32
#define FAST_WS_BYTES 338048u

// fallback (R3) layout
#define Z_OFF    0u
#define CNT_OFF  32768u
#define PSUM_OFF 32832u

__device__ inline u16 f2bf(float f){
  union { float f; u32 u; } v; v.f = f;
  u32 r = v.u + 0x7fffu + ((v.u >> 16) & 1u);   // RNE
  return (u16)(r >> 16);
}
__device__ inline u32 pk2(float a, float b){ return (u32)f2bf(a) | ((u32)f2bf(b)<<16); }
__device__ inline float geluf(float x){ return 0.5f*x*(1.0f+erff(x*0.70710678118654752f)); }

// ================= k0: pack weights to MFMA A-frag layout, zero accumulators ==========
// A-frag: lane l holds m=l&15, k=kc*32+(l>>4)*8+j ; packed idx = ((kc*MT+mt)*64+lane)*8+j
// task-space region boundaries 12288/16384/17408/82944/148480 are all ≡0 mod 512.
__global__ __launch_bounds__(256) void k0_pack(
    const float* __restrict__ w1, const float* __restrict__ w2, const float* __restrict__ gw,
    const float* __restrict__ e1, const float* __restrict__ e2,
    u16* w1p, u16* w2p, u16* gwp, u16* e1p, u16* e2p,
    float* z, u32* cnt, float* psum)
{
  int gid = blockIdx.x*256 + threadIdx.x;
  if (gid < 8192) z[gid] = 0.f;
  else if (gid < 8196) cnt[gid-8192] = 0u;
  else if (gid < 8200) psum[gid-8196] = 0.f;

  int p = gid;
  int j = p & 7, lane = (p>>3) & 63;
  int col = lane & 15, q = lane >> 4;
  if (p < 12288){                         // w1p: KC=6, MT=4 (M=64,K=192)
    int tile = p >> 9, kc = tile >> 2, mt = tile & 3;
    int k = kc*32 + q*8 + j, m = mt*16 + col;
    w1p[p] = f2bf(w1[k*64 + m]); return;
  }
  p -= 12288;
  if (p < 4096){                          // w2p: KC=2, MT=4 (M=64,K=64)
    int tile = p >> 9, kc = tile >> 2, mt = tile & 3;
    int k = kc*32 + q*8 + j, m = mt*16 + col;
    w2p[p] = f2bf(w2[k*64 + m]); return;
  }
  p -= 4096;
  if (p < 1024){                          // gwp: KC=2, M=4 zero-padded to 16
    int kc = p >> 9;
    int k = kc*32 + q*8 + j, m = col;
    gwp[p] = (m < 4) ? f2bf(gw[k*4 + m]) : (u16)0; return;
  }
  p -= 1024;
  if (p < 65536){                         // e1p: per e: KC=2, MT=16 (M=256,K=64)
    int e = p >> 14, pp = p & 16383;
    int tile = pp >> 9, kc = tile >> 4, mt = tile & 15;
    int k = kc*32 + q*8 + j, m = mt*16 + col;
    e1p[p] = f2bf(e1[e*16384 + k*256 + m]); return;
  }
  p -= 65536;
  if (p < 65536){                         // e2p: per e: KC=8, MT=4 (M=64,K=256)
    int e = p >> 14, pp = p & 16383;
    int tile = pp >> 9, kc = tile >> 2, mt = tile & 3;
    int k = kc*32 + q*8 + j, m = mt*16 + col;
    e2p[p] = f2bf(e2[e*16384 + k*64 + m]); return;
  }
}

// ================= kMain: fused dense pipeline, 64 tokens per block ===================
__global__ __launch_bounds__(256) void kMain(
    const float* __restrict__ x,
    const float* __restrict__ b1, const float* __restrict__ b2, const float* __restrict__ gb,
    const u16* __restrict__ w1p, const u16* __restrict__ w2p, const u16* __restrict__ gwp,
    const u16* __restrict__ e1p, const u16* __restrict__ e2p,
    const float* __restrict__ eb1, const float* __restrict__ eb2,
    float* __restrict__ z, u32* __restrict__ cnt, float* __restrict__ psum)
{
  __shared__ char xh[32768];      // x tile (64x384B), later aliased by hid (64x512B)
  __shared__ char h1l[8192];      // 64x128B
  __shared__ char hl[8192];       // 64x128B
  __shared__ float part[256];     // [wave][64] pooled partials
  __shared__ int   be_s[64];
  __shared__ float gv_s[64];
  __shared__ float lgp[4];
  __shared__ u32   lgc[4];

  const int tid  = threadIdx.x;
  const int tok0 = blockIdx.x * 64;
  if (tid < 4){ lgp[tid] = 0.f; lgc[tid] = 0u; }

  // ---- stage x -> bf16 LDS (rows = 24 x 16B chunks, XOR-swizzled) ----
  for (int it = 0; it < 6; ++it){
    int task = tid + it*256;               // 1536 tasks
    int t = task / 24, c = task % 24;
    const float4* gp = (const float4*)(x + (size_t)(tok0 + t)*192 + c*8);
    float4 f0 = gp[0], f1 = gp[1];
    uint4 v;
    v.x = pk2(f0.x, f0.y); v.y = pk2(f0.z, f0.w);
    v.z = pk2(f1.x, f1.y); v.w = pk2(f1.z, f1.w);
    *(uint4*)(xh + t*384 + ((c ^ (t & 7)) * 16)) = v;
  }
  __syncthreads();

  const int lane = tid & 63, wave = tid >> 6;
  const int col  = lane & 15, quad = lane >> 4;
  const int t    = wave*16 + col;          // this lane's token (MFMA n-col)

  // ---- GEMM1 (swapped): h1T[m][t] = sum_k W1[k][m] * x[t][k], + bias + GELU ----
  {
    bf16x8 bx[6];
    for (int kc = 0; kc < 6; ++kc)
      bx[kc] = *(const bf16x8*)(xh + t*384 + (((4*kc + quad) ^ (t & 7)) * 16));
    for (int mt = 0; mt < 4; ++mt){
      float4v acc = {0.f,0.f,0.f,0.f};
      for (int kc = 0; kc < 6; ++kc){
        bf16x8 a = *(const bf16x8*)(w1p + ((kc*4 + mt)*64 + lane)*8);
        acc = MFMA16(a, bx[kc], acc);
      }
      int j0 = mt*16 + quad*4;
      float v0 = geluf(acc[0] + b1[j0+0]);
      float v1 = geluf(acc[1] + b1[j0+1]);
      float v2 = geluf(acc[2] + b1[j0+2]);
      float v3 = geluf(acc[3] + b1[j0+3]);
      uint2 w; w.x = pk2(v0,v1); w.y = pk2(v2,v3);
      *(uint2*)(h1l + t*128 + (((2*mt + (quad>>1)) ^ (t & 7))*16) + (quad & 1)*8) = w;
    }
  }
  __syncthreads();

  // ---- GEMM2 (swapped): hT = W2^T * h1T + bias ----
  {
    bf16x8 bh1[2];
    for (int kc = 0; kc < 2; ++kc)
      bh1[kc] = *(const bf16x8*)(h1l + t*128 + (((4*kc + quad) ^ (t & 7))*16));
    for (int mt = 0; mt < 4; ++mt){
      float4v acc = {0.f,0.f,0.f,0.f};
      for (int kc = 0; kc < 2; ++kc){
        bf16x8 a = *(const bf16x8*)(w2p + ((kc*4 + mt)*64 + lane)*8);
        acc = MFMA16(a, bh1[kc], acc);
      }
      int j0 = mt*16 + quad*4;
      uint2 w; w.x = pk2(acc[0]+b2[j0+0], acc[1]+b2[j0+1]);
               w.y = pk2(acc[2]+b2[j0+2], acc[3]+b2[j0+3]);
      *(uint2*)(hl + t*128 + (((2*mt + (quad>>1)) ^ (t & 7))*16) + (quad & 1)*8) = w;
    }
  }
  __syncthreads();

  // ---- h B-frag (reused by gate and all experts) ----
  bf16x8 bh[2];
  for (int kc = 0; kc < 2; ++kc)
    bh[kc] = *(const bf16x8*)(hl + t*128 + (((4*kc + quad) ^ (t & 7))*16));

  // ---- gate: logits via MFMA; softmax/top-1 by quad-0 lanes ----
  {
    float4v ag = {0.f,0.f,0.f,0.f};
    for (int kc = 0; kc < 2; ++kc){
      bf16x8 a = *(const bf16x8*)(gwp + (kc*64 + lane)*8);
      ag = MFMA16(a, bh[kc], ag);
    }
    if (quad == 0){
      float l0 = ag[0]+gb[0], l1 = ag[1]+gb[1], l2 = ag[2]+gb[2], l3 = ag[3]+gb[3];
      float mx = fmaxf(fmaxf(l0,l1), fmaxf(l2,l3));
      float x0 = expf(l0-mx), x1 = expf(l1-mx), x2 = expf(l2-mx), x3 = expf(l3-mx);
      float inv = 1.f/(x0+x1+x2+x3);
      float p0 = x0*inv, p1 = x1*inv, p2 = x2*inv, p3 = x3*inv;
      int be = 0; float bv = l0;
      if (l1 > bv){ bv = l1; be = 1; }
      if (l2 > bv){ bv = l2; be = 2; }
      if (l3 > bv){ bv = l3; be = 3; }
      be_s[t] = be;
      gv_s[t] = (be==0) ? p0 : (be==1) ? p1 : (be==2) ? p2 : p3;
      atomicAdd(&lgp[0], p0); atomicAdd(&lgp[1], p1);
      atomicAdd(&lgp[2], p2); atomicAdd(&lgp[3], p3);
      atomicAdd(&lgc[be], 1u);
    }
  }

  // ---- all 4 experts, dense; combine with onehot*gate in registers ----
  float oacc[16];
  for (int i = 0; i < 16; ++i) oacc[i] = 0.f;
  for (int e = 0; e < 4; ++e){
    const u16* W1 = e1p + e*16384;
    const u16* W2 = e2p + e*16384;
    __syncthreads();                       // hid (aliases xh) overwrite guard
    // L1: hidT[j][t], M=256, K=64
    for (int mt = 0; mt < 16; ++mt){
      float4v acc = {0.f,0.f,0.f,0.f};
      for (int kc = 0; kc < 2; ++kc){
        bf16x8 a = *(const bf16x8*)(W1 + ((kc*16 + mt)*64 + lane)*8);
        acc = MFMA16(a, bh[kc], acc);
      }
      int j0 = mt*16 + quad*4;
      float v0 = geluf(acc[0] + eb1[e*256 + j0+0]);
      float v1 = geluf(acc[1] + eb1[e*256 + j0+1]);
      float v2 = geluf(acc[2] + eb1[e*256 + j0+2]);
      float v3 = geluf(acc[3] + eb1[e*256 + j0+3]);
      uint2 w; w.x = pk2(v0,v1); w.y = pk2(v2,v3);
      *(uint2*)(xh + t*512 + (((2*mt + (quad>>1)) ^ (t & 7))*16) + (quad & 1)*8) = w;
    }
    __syncthreads();
    // L2: outT[d][t], M=64, K=256
    bf16x8 bhid[8];
    for (int kc = 0; kc < 8; ++kc)
      bhid[kc] = *(const bf16x8*)(xh + t*512 + (((4*kc + quad) ^ (t & 7))*16));
    float wgt = (be_s[t] == e) ? gv_s[t] : 0.f;
    for (int mt = 0; mt < 4; ++mt){
      float4v acc = {0.f,0.f,0.f,0.f};
      for (int kc = 0; kc < 8; ++kc){
        bf16x8 a = *(const bf16x8*)(W2 + ((kc*4 + mt)*64 + lane)*8);
        acc = MFMA16(a, bhid[kc], acc);
      }
      int j0 = mt*16 + quad*4;
      oacc[mt*4+0] += (acc[0] + eb2[e*64 + j0+0]) * wgt;
      oacc[mt*4+1] += (acc[1] + eb2[e*64 + j0+1]) * wgt;
      oacc[mt*4+2] += (acc[2] + eb2[e*64 + j0+2]) * wgt;
      oacc[mt*4+3] += (acc[3] + eb2[e*64 + j0+3]) * wgt;
    }
  }

  // ---- pooled reduction over this block's 64 tokens ----
  for (int m = 1; m < 16; m <<= 1)
    for (int i = 0; i < 16; ++i)
      oacc[i] += __shfl_xor(oacc[i], m, 64);   // sum over the 16 cols (tokens) of the wave
  if (col == 0){
    for (int mt = 0; mt < 4; ++mt)
      for (int r = 0; r < 4; ++r)
        part[wave*64 + mt*16 + quad*4 + r] = oacc[mt*4 + r];
  }
  __syncthreads();
  int b = blockIdx.x >> 4;                 // 16 blocks per batch row
  if (tid < 64){
    float s = part[tid] + part[64+tid] + part[128+tid] + part[192+tid];
    atomicAdd(&z[b*64 + tid], s);
  }
  if (tid < 4){ atomicAdd(&cnt[tid], lgc[tid]); atomicAdd(&psum[tid], lgp[tid]); }
}

// ================= kFinal: mean pool + LayerNorm + classifier (+aux) ==================
__global__ __launch_bounds__(64) void kFinal(
    const float* __restrict__ z, const u32* __restrict__ cnt, const float* __restrict__ psum,
    const float* __restrict__ ln_g, const float* __restrict__ ln_b,
    const float* __restrict__ cw1, const float* __restrict__ cb1,
    const float* __restrict__ cw2, const float* __restrict__ cb2,
    float* __restrict__ out)
{
  __shared__ float z_l[64], zn_l[64], c1_l[64], red[2];
  int tid = threadIdx.x, b = blockIdx.x;
  z_l[tid] = z[b*64 + tid] * (1.0f/1024.0f);
  __syncthreads();
  if (tid == 0){
    float mu = 0.f; for (int i=0;i<64;++i) mu += z_l[i]; mu *= (1.f/64.f);
    float vv = 0.f; for (int i=0;i<64;++i){ float d=z_l[i]-mu; vv += d*d; } vv *= (1.f/64.f);
    red[0]=mu; red[1]=1.0f/sqrtf(vv+1e-5f);
  }
  __syncthreads();
  zn_l[tid] = (z_l[tid]-red[0])*red[1]*ln_g[tid] + ln_b[tid];
  __syncthreads();
  float a1 = cb1[tid];
  for (int k=0;k<64;++k) a1 += zn_l[k]*cw1[k*64+tid];
  c1_l[tid] = geluf(a1);
  __syncthreads();
  if (tid < 10){
    float y = cb2[tid];
    for (int k=0;k<64;++k) y += c1_l[k]*cw2[k*10+tid];
    out[b*10+tid] = y;
  }
  if (b == 0 && tid == 0){
    float aux = 0.f;
    for (int e=0;e<4;++e) aux += (float)cnt[e]*psum[e];
    out[1280] = 4.0f*aux/(131072.0f*131072.0f);
  }
}

// ================= fallback path (verified R3 fp32 kernels) ===========================
__global__ __launch_bounds__(256) void kInitF(float* z, u32* cnt, float* psum){
  int i = blockIdx.x*256 + threadIdx.x;
  if (i < 8192) z[i] = 0.f;
  if (i < 4){ cnt[i] = 0u; psum[i] = 0.f; }
}

__global__ __launch_bounds__(256) void kFusedF(
    const float* __restrict__ x,
    const float* __restrict__ w1, const float* __restrict__ b1,
    const float* __restrict__ w2, const float* __restrict__ b2,
    const float* __restrict__ gw, const float* __restrict__ gb,
    const float* __restrict__ e1, const float* __restrict__ eb1,
    const float* __restrict__ e2, const float* __restrict__ eb2,
    float* __restrict__ z, u32* __restrict__ cnt, float* __restrict__ psum)
{
  __shared__ float xs[4][192];
  __shared__ float h1s[4][64];
  __shared__ float hs[4][64];
  __shared__ float hid[4][256];
  __shared__ float lg[4][4];
  __shared__ int   be_s[4];
  __shared__ float gv_s[4];
  __shared__ float lgp[4];
  __shared__ u32   lgc[4];
  const int tid  = threadIdx.x;
  const int w    = tid >> 6, lane = tid & 63;
  const int tok  = blockIdx.x*4 + w;
  if (tid < 4){ lgp[tid] = 0.f; lgc[tid] = 0u; }
  for (int r = 0; r < 3; ++r)
    xs[w][lane + 64*r] = x[(size_t)tok*192 + lane + 64*r];
  __syncthreads();
  float a = b1[lane];
  for (int k = 0; k < 192; ++k) a += xs[w][k]*w1[k*64 + lane];
  h1s[w][lane] = geluf(a);
  __syncthreads();
  float h = b2[lane];
  for (int k = 0; k < 64; ++k) h += h1s[w][k]*w2[k*64 + lane];
  hs[w][lane] = h;
  __syncthreads();
  if (lane < 4){
    float l = gb[lane];
    for (int k = 0; k < 64; ++k) l += hs[w][k]*gw[k*4 + lane];
    lg[w][lane] = l;
  }
  __syncthreads();
  if (lane == 0){
    float l0=lg[w][0], l1=lg[w][1], l2=lg[w][2], l3=lg[w][3];
    float mx = fmaxf(fmaxf(l0,l1),fmaxf(l2,l3));
    float x0=expf(l0-mx), x1=expf(l1-mx), x2=expf(l2-mx), x3=expf(l3-mx);
    float inv = 1.f/(x0+x1+x2+x3);
    float p0=x0*inv, p1=x1*inv, p2=x2*inv, p3=x3*inv;
    int be=0; float bv=l0;
    if (l1>bv){bv=l1;be=1;}
    if (l2>bv){bv=l2;be=2;}
    if (l3>bv){bv=l3;be=3;}
    be_s[w]=be;
    gv_s[w]=(be==0)?p0:(be==1)?p1:(be==2)?p2:p3;
    atomicAdd(&lgp[0],p0); atomicAdd(&lgp[1],p1);
    atomicAdd(&lgp[2],p2); atomicAdd(&lgp[3],p3);
    atomicAdd(&lgc[be],1u);
  }
  __syncthreads();
  const int e    = be_s[w];
  const float gv = gv_s[w];
  const float* W1 = e1 + e*16384;
  const float* W2 = e2 + e*16384;
  for (int q = 0; q < 4; ++q){
    int j = q*64 + lane;
    float s = eb1[e*256 + j];
    for (int k = 0; k < 64; ++k) s += hs[w][k]*W1[k*256 + j];
    hid[w][j] = geluf(s);
  }
  __syncthreads();
  float o = eb2[e*64 + lane];
  for (int j = 0; j < 256; ++j) o += hid[w][j]*W2[j*64 + lane];
  int b = tok >> 10;
  atomicAdd(&z[b*64 + lane], o*gv);
  __syncthreads();
  if (tid < 4){ atomicAdd(&cnt[tid], lgc[tid]); atomicAdd(&psum[tid], lgp[tid]); }
}

// ======================================================================================
extern "C" void kernel_launch(void* const* d_in, const int* in_sizes, int n_in,
                              void* d_out, int out_size, void* d_ws, size_t ws_size,
                              hipStream_t stream)
{
  const float* x    = (const float*)d_in[0];
  const float* pw1  = (const float*)d_in[1];
  const float* pb1  = (const float*)d_in[2];
  const float* pw2  = (const float*)d_in[3];
  const float* pb2  = (const float*)d_in[4];
  const float* gw   = (const float*)d_in[5];
  const float* gb   = (const float*)d_in[6];
  const float* ew1  = (const float*)d_in[7];
  const float* eb1  = (const float*)d_in[8];
  const float* ew2  = (const float*)d_in[9];
  const float* eb2  = (const float*)d_in[10];
  const float* lng  = (const float*)d_in[11];
  const float* lnb  = (const float*)d_in[12];
  const float* cw1  = (const float*)d_in[13];
  const float* cb1  = (const float*)d_in[14];
  const float* cw2  = (const float*)d_in[15];
  const float* cb2  = (const float*)d_in[16];
  char* ws  = (char*)d_ws;
  float* out = (float*)d_out;

  if (ws_size >= FAST_WS_BYTES){
    u16*  w1p  = (u16*)(ws + W1P_OFF);
    u16*  w2p  = (u16*)(ws + W2P_OFF);
    u16*  gwp  = (u16*)(ws + GWP_OFF);
    u16*  e1p  = (u16*)(ws + E1P_OFF);
    u16*  e2p  = (u16*)(ws + E2P_OFF);
    float* z    = (float*)(ws + ZF_OFF);
    u32*  cnt  = (u32*)(ws + CNTF_OFF);
    float* psum = (float*)(ws + PSUMF_OFF);
    k0_pack<<<580, 256, 0, stream>>>(pw1, pw2, gw, ew1, ew2,
                                     w1p, w2p, gwp, e1p, e2p, z, cnt, psum);
    kMain <<<2048, 256, 0, stream>>>(x, pb1, pb2, gb, w1p, w2p, gwp, e1p, e2p,
                                     eb1, eb2, z, cnt, psum);
    kFinal<<<128, 64, 0, stream>>>(z, cnt, psum, lng, lnb, cw1, cb1, cw2, cb2, out);
  } else {
    float* z    = (float*)(ws + Z_OFF);
    u32*   cnt  = (u32*)(ws + CNT_OFF);
    float* psum = (float*)(ws + PSUM_OFF);
    kInitF <<<32,    256, 0, stream>>>(z, cnt, psum);
    kFusedF<<<32768, 256, 0, stream>>>(x, pw1, pb1, pw2, pb2, gw, gb,
                                       ew1, eb1, ew2, eb2, z, cnt, psum);
    kFinal <<<128,   64,  0, stream>>>(z, cnt, psum, lng, lnb, cw1, cb1, cw2, cb2, out);
  }
}

// Round 5
// 277.600 us; speedup vs baseline: 3.6405x; 1.4153x over previous
//
#include <hip/hip_runtime.h>
#include <math.h>

typedef unsigned int  u32;
typedef unsigned short u16;
typedef unsigned long long u64;

using bf16x8  = __attribute__((ext_vector_type(8))) __bf16;
using float4v = __attribute__((ext_vector_type(4))) float;

#define MFMA16(a,b,c) __builtin_amdgcn_mfma_f32_16x16x32_bf16(a,b,c,0,0,0)

// ---- fast-path workspace layout (bytes) — total 338 KB ----
#define W1P_OFF   0u          // 12288 u16
#define W2P_OFF   24576u      // 4096 u16
#define GWP_OFF   40960u      // 1024 u16 (gate padded to m=16)
#define E1P_OFF   43008u      // 65536 u16 (4 experts x 16384)
#define E2P_OFF   174080u     // 65536 u16 (4 experts x 16384)
#define ZF_OFF    305152u     // 8192 f32
#define CNTF_OFF  337920u     // 4 u32
#define PSUMF_OFF 337984u     // 4 f32
#define FAST_WS_BYTES 338048u

// fallback (R3) layout
#define Z_OFF    0u
#define CNT_OFF  32768u
#define PSUM_OFF 32832u

__device__ inline u16 f2bf(float f){
  union { float f; u32 u; } v; v.f = f;
  u32 r = v.u + 0x7fffu + ((v.u >> 16) & 1u);   // RNE
  return (u16)(r >> 16);
}
__device__ inline u32 pk2(float a, float b){ return (u32)f2bf(a) | ((u32)f2bf(b)<<16); }

// GELU via Abramowitz-Stegun 7.1.26 erf (|err|<=1.5e-7, branchless, ~20 inst
// vs ~60 for divergent libm erff). gelu(x)=0.5x(1+erf(x/sqrt2)).
__device__ inline float geluf(float x){
  float u = fabsf(x) * 0.70710678118654752f;
  float t = 1.0f / (1.0f + 0.3275911f * u);
  float poly = t*(0.254829592f + t*(-0.284496736f +
               t*(1.421413741f + t*(-1.453152027f + t*1.061405429f))));
  float er = 1.0f - poly * __expf(-u*u);
  return 0.5f * x * (1.0f + copysignf(er, x));
}

// ================= k0: pack weights to MFMA A-frag layout (coalesced reads) ===========
// A-frag: lane l holds m=l&15, k=kc*32+(l>>4)*8+j ; packed idx = ((kc*MT+mt)*64+lane)*8+j
__global__ __launch_bounds__(256) void k0_pack(
    const float* __restrict__ w1, const float* __restrict__ w2, const float* __restrict__ gw,
    const float* __restrict__ e1, const float* __restrict__ e2,
    u16* w1p, u16* w2p, u16* gwp, u16* e1p, u16* e2p,
    float* z, u32* cnt, float* psum)
{
  int p = blockIdx.x*256 + threadIdx.x;
  if (p < 12288){                         // w1 [192][64] -> KC=6,MT=4
    int k = p >> 6, m = p & 63;
    int kc = k>>5, q = (k>>3)&3, j = k&7, mt = m>>4, col = m&15;
    w1p[((kc*4+mt)*64 + q*16+col)*8 + j] = f2bf(w1[p]); return;
  }
  p -= 12288;
  if (p < 4096){                          // w2 [64][64] -> KC=2,MT=4
    int k = p >> 6, m = p & 63;
    int kc = k>>5, q = (k>>3)&3, j = k&7, mt = m>>4, col = m&15;
    w2p[((kc*4+mt)*64 + q*16+col)*8 + j] = f2bf(w2[p]); return;
  }
  p -= 4096;
  if (p < 1024){                          // gw [64][4] -> KC=2, M=4 zero-pad to 16 (dest-indexed)
    int j = p & 7, lane = (p>>3) & 63;
    int col = lane & 15, q = lane >> 4, kc = p >> 9;
    int k = kc*32 + q*8 + j;
    gwp[p] = (col < 4) ? f2bf(gw[k*4 + col]) : (u16)0; return;
  }
  p -= 1024;
  if (p < 65536){                         // e1 [e][64][256] -> per e: KC=2,MT=16
    int e = p >> 14, r = p & 16383;
    int k = r >> 8, m = r & 255;
    int kc = k>>5, q = (k>>3)&3, j = k&7, mt = m>>4, col = m&15;
    e1p[e*16384 + ((kc*16+mt)*64 + q*16+col)*8 + j] = f2bf(e1[p]); return;
  }
  p -= 65536;
  if (p < 65536){                         // e2 [e][256][64] -> per e: KC=8,MT=4
    int e = p >> 14, r = p & 16383;
    int k = r >> 6, m = r & 63;
    int kc = k>>5, q = (k>>3)&3, j = k&7, mt = m>>4, col = m&15;
    e2p[e*16384 + ((kc*4+mt)*64 + q*16+col)*8 + j] = f2bf(e2[p]); return;
  }
  p -= 65536;
  if (p < 8192){ z[p] = 0.f; return; }
  p -= 8192;
  if (p < 4){ cnt[p] = 0u; return; }
  p -= 4;
  if (p < 4){ psum[p] = 0.f; return; }
}

// ================= kMain: fused pipeline + in-block expert compaction =================
__global__ __launch_bounds__(256) void kMain(
    const float* __restrict__ x,
    const float* __restrict__ b1, const float* __restrict__ b2, const float* __restrict__ gb,
    const u16* __restrict__ w1p, const u16* __restrict__ w2p, const u16* __restrict__ gwp,
    const u16* __restrict__ e1p, const u16* __restrict__ e2p,
    const float* __restrict__ eb1, const float* __restrict__ eb2,
    float* __restrict__ z, u32* __restrict__ cnt, float* __restrict__ psum)
{
  __shared__ char xh[32768];      // x tile (64x384B); later per-wave hid tiles (4 x 16x512B)
  __shared__ char h1l[8192];      // 64x128B
  __shared__ char hl[8192];       // 64x128B
  __shared__ float part[256];
  __shared__ int   be_s[64];
  __shared__ float gv_s[64];
  __shared__ int   sperm[64];     // sorted-by-expert token order
  __shared__ int   se_s[64];      // expert at sorted slot
  __shared__ float sg_s[64];      // gate at sorted slot
  __shared__ float lgp[4];
  __shared__ u32   lgc[4];

  const int tid  = threadIdx.x;
  const int tok0 = blockIdx.x * 64;
  if (tid < 4){ lgp[tid] = 0.f; lgc[tid] = 0u; }

  // ---- stage x -> bf16 LDS (rows = 24 x 16B chunks, XOR-swizzled) ----
  for (int it = 0; it < 6; ++it){
    int task = tid + it*256;               // 1536 tasks
    int t = task / 24, c = task % 24;
    const float4* gp = (const float4*)(x + (size_t)(tok0 + t)*192 + c*8);
    float4 f0 = gp[0], f1 = gp[1];
    uint4 v;
    v.x = pk2(f0.x, f0.y); v.y = pk2(f0.z, f0.w);
    v.z = pk2(f1.x, f1.y); v.w = pk2(f1.z, f1.w);
    *(uint4*)(xh + t*384 + ((c ^ (t & 7)) * 16)) = v;
  }
  __syncthreads();

  const int lane = tid & 63, wave = tid >> 6;
  const int col  = lane & 15, quad = lane >> 4;
  const int t    = wave*16 + col;          // own token (MFMA n-col)

  // ---- GEMM1: h1T[m][t] = gelu(W1^T x + b1) ----
  {
    bf16x8 bx[6];
    for (int kc = 0; kc < 6; ++kc)
      bx[kc] = *(const bf16x8*)(xh + t*384 + (((4*kc + quad) ^ (t & 7)) * 16));
    for (int mt = 0; mt < 4; ++mt){
      float4v acc = {0.f,0.f,0.f,0.f};
      for (int kc = 0; kc < 6; ++kc){
        bf16x8 a = *(const bf16x8*)(w1p + ((kc*4 + mt)*64 + lane)*8);
        acc = MFMA16(a, bx[kc], acc);
      }
      int j0 = mt*16 + quad*4;
      float v0 = geluf(acc[0] + b1[j0+0]);
      float v1 = geluf(acc[1] + b1[j0+1]);
      float v2 = geluf(acc[2] + b1[j0+2]);
      float v3 = geluf(acc[3] + b1[j0+3]);
      uint2 w; w.x = pk2(v0,v1); w.y = pk2(v2,v3);
      *(uint2*)(h1l + t*128 + (((2*mt + (quad>>1)) ^ (t & 7))*16) + (quad & 1)*8) = w;
    }
  }
  __syncthreads();

  // ---- GEMM2: hT = W2^T h1 + b2 ----
  {
    bf16x8 bh1[2];
    for (int kc = 0; kc < 2; ++kc)
      bh1[kc] = *(const bf16x8*)(h1l + t*128 + (((4*kc + quad) ^ (t & 7))*16));
    for (int mt = 0; mt < 4; ++mt){
      float4v acc = {0.f,0.f,0.f,0.f};
      for (int kc = 0; kc < 2; ++kc){
        bf16x8 a = *(const bf16x8*)(w2p + ((kc*4 + mt)*64 + lane)*8);
        acc = MFMA16(a, bh1[kc], acc);
      }
      int j0 = mt*16 + quad*4;
      uint2 w; w.x = pk2(acc[0]+b2[j0+0], acc[1]+b2[j0+1]);
               w.y = pk2(acc[2]+b2[j0+2], acc[3]+b2[j0+3]);
      *(uint2*)(hl + t*128 + (((2*mt + (quad>>1)) ^ (t & 7))*16) + (quad & 1)*8) = w;
    }
  }
  __syncthreads();

  // ---- gate: logits via MFMA; softmax/top-1 by quad-0 lanes ----
  {
    bf16x8 bh[2];
    for (int kc = 0; kc < 2; ++kc)
      bh[kc] = *(const bf16x8*)(hl + t*128 + (((4*kc + quad) ^ (t & 7))*16));
    float4v ag = {0.f,0.f,0.f,0.f};
    for (int kc = 0; kc < 2; ++kc){
      bf16x8 a = *(const bf16x8*)(gwp + (kc*64 + lane)*8);
      ag = MFMA16(a, bh[kc], ag);
    }
    if (quad == 0){
      float l0 = ag[0]+gb[0], l1 = ag[1]+gb[1], l2 = ag[2]+gb[2], l3 = ag[3]+gb[3];
      float mx = fmaxf(fmaxf(l0,l1), fmaxf(l2,l3));
      float x0 = expf(l0-mx), x1 = expf(l1-mx), x2 = expf(l2-mx), x3 = expf(l3-mx);
      float inv = 1.f/(x0+x1+x2+x3);
      float p0 = x0*inv, p1 = x1*inv, p2 = x2*inv, p3 = x3*inv;
      int be = 0; float bv = l0;
      if (l1 > bv){ bv = l1; be = 1; }
      if (l2 > bv){ bv = l2; be = 2; }
      if (l3 > bv){ bv = l3; be = 3; }
      be_s[t] = be;
      gv_s[t] = (be==0) ? p0 : (be==1) ? p1 : (be==2) ? p2 : p3;
      atomicAdd(&lgp[0], p0); atomicAdd(&lgp[1], p1);
      atomicAdd(&lgp[2], p2); atomicAdd(&lgp[3], p3);
      atomicAdd(&lgc[be], 1u);
    }
  }
  __syncthreads();

  // ---- wave 0: stable sort of 64 tokens by expert via ballot ranks ----
  if (tid < 64){
    int e = be_s[tid];
    u64 m0 = __ballot(e==0), m1 = __ballot(e==1), m2 = __ballot(e==2), m3 = __ballot(e==3);
    int c0 = __popcll(m0), c1 = __popcll(m1), c2 = __popcll(m2);
    int base = (e==0) ? 0 : (e==1) ? c0 : (e==2) ? c0+c1 : c0+c1+c2;
    u64 me = (e==0) ? m0 : (e==1) ? m1 : (e==2) ? m2 : m3;
    int pos = base + __popcll(me & ((1ull<<tid)-1ull));
    sperm[pos] = tid; se_s[pos] = e; sg_s[pos] = gv_s[tid];
  }
  __syncthreads();

  // ---- per-wave expert loop on its sorted 16-token slice ----
  const int slice = wave*16;
  const int tt    = sperm[slice + col];       // permuted token for this MFMA col
  const int myE   = se_s[slice + col];
  const float myG = sg_s[slice + col];
  const int e_lo  = se_s[slice], e_hi = se_s[slice + 15];
  char* hb = xh + wave*8192;                  // wave-private hid tile (16 x 512B)

  bf16x8 bhp[2];
  for (int kc = 0; kc < 2; ++kc)
    bhp[kc] = *(const bf16x8*)(hl + tt*128 + (((4*kc + quad) ^ (tt & 7))*16));

  float oacc[16];
  for (int i = 0; i < 16; ++i) oacc[i] = 0.f;

  for (int e = e_lo; e <= e_hi; ++e){
    const u16* W1 = e1p + e*16384;
    const u16* W2 = e2p + e*16384;
    // L1: hidT[j][tok], M=256, K=64 (wave-private, no block barrier needed)
    for (int mt = 0; mt < 16; ++mt){
      float4v acc = {0.f,0.f,0.f,0.f};
      for (int kc = 0; kc < 2; ++kc){
        bf16x8 a = *(const bf16x8*)(W1 + ((kc*16 + mt)*64 + lane)*8);
        acc = MFMA16(a, bhp[kc], acc);
      }
      int j0 = mt*16 + quad*4;
      float v0 = geluf(acc[0] + eb1[e*256 + j0+0]);
      float v1 = geluf(acc[1] + eb1[e*256 + j0+1]);
      float v2 = geluf(acc[2] + eb1[e*256 + j0+2]);
      float v3 = geluf(acc[3] + eb1[e*256 + j0+3]);
      uint2 w; w.x = pk2(v0,v1); w.y = pk2(v2,v3);
      *(uint2*)(hb + col*512 + (((2*mt + (quad>>1)) ^ (col & 7))*16) + (quad & 1)*8) = w;
    }
    // L2: outT[d][tok], M=64, K=256; accumulate with onehot*gate mask
    bf16x8 bhid[8];
    for (int kc = 0; kc < 8; ++kc)
      bhid[kc] = *(const bf16x8*)(hb + col*512 + (((4*kc + quad) ^ (col & 7))*16));
    float wgt = (myE == e) ? myG : 0.f;
    for (int mt = 0; mt < 4; ++mt){
      float4v acc = {0.f,0.f,0.f,0.f};
      for (int kc = 0; kc < 8; ++kc){
        bf16x8 a = *(const bf16x8*)(W2 + ((kc*4 + mt)*64 + lane)*8);
        acc = MFMA16(a, bhid[kc], acc);
      }
      int j0 = mt*16 + quad*4;
      oacc[mt*4+0] += (acc[0] + eb2[e*64 + j0+0]) * wgt;
      oacc[mt*4+1] += (acc[1] + eb2[e*64 + j0+1]) * wgt;
      oacc[mt*4+2] += (acc[2] + eb2[e*64 + j0+2]) * wgt;
      oacc[mt*4+3] += (acc[3] + eb2[e*64 + j0+3]) * wgt;
    }
  }

  // ---- pooled reduction over the block's 64 tokens (cols) ----
  for (int m = 1; m < 16; m <<= 1)
    for (int i = 0; i < 16; ++i)
      oacc[i] += __shfl_xor(oacc[i], m, 64);
  if (col == 0){
    for (int mt = 0; mt < 4; ++mt)
      for (int r = 0; r < 4; ++r)
        part[wave*64 + mt*16 + quad*4 + r] = oacc[mt*4 + r];
  }
  __syncthreads();
  int b = blockIdx.x >> 4;                 // 16 blocks per batch row
  if (tid < 64){
    float s = part[tid] + part[64+tid] + part[128+tid] + part[192+tid];
    atomicAdd(&z[b*64 + tid], s);
  }
  if (tid < 4){ atomicAdd(&cnt[tid], lgc[tid]); atomicAdd(&psum[tid], lgp[tid]); }
}

// ================= kFinal: mean pool + LayerNorm + classifier (+aux) ==================
__global__ __launch_bounds__(64) void kFinal(
    const float* __restrict__ z, const u32* __restrict__ cnt, const float* __restrict__ psum,
    const float* __restrict__ ln_g, const float* __restrict__ ln_b,
    const float* __restrict__ cw1, const float* __restrict__ cb1,
    const float* __restrict__ cw2, const float* __restrict__ cb2,
    float* __restrict__ out)
{
  __shared__ float z_l[64], zn_l[64], c1_l[64], red[2];
  int tid = threadIdx.x, b = blockIdx.x;
  z_l[tid] = z[b*64 + tid] * (1.0f/1024.0f);
  __syncthreads();
  if (tid == 0){
    float mu = 0.f; for (int i=0;i<64;++i) mu += z_l[i]; mu *= (1.f/64.f);
    float vv = 0.f; for (int i=0;i<64;++i){ float d=z_l[i]-mu; vv += d*d; } vv *= (1.f/64.f);
    red[0]=mu; red[1]=1.0f/sqrtf(vv+1e-5f);
  }
  __syncthreads();
  zn_l[tid] = (z_l[tid]-red[0])*red[1]*ln_g[tid] + ln_b[tid];
  __syncthreads();
  float a1 = cb1[tid];
  for (int k=0;k<64;++k) a1 += zn_l[k]*cw1[k*64+tid];
  c1_l[tid] = geluf(a1);
  __syncthreads();
  if (tid < 10){
    float y = cb2[tid];
    for (int k=0;k<64;++k) y += c1_l[k]*cw2[k*10+tid];
    out[b*10+tid] = y;
  }
  if (b == 0 && tid == 0){
    float aux = 0.f;
    for (int e=0;e<4;++e) aux += (float)cnt[e]*psum[e];
    out[1280] = 4.0f*aux/(131072.0f*131072.0f);
  }
}

// ================= fallback path (verified R3 fp32 kernels) ===========================
__global__ __launch_bounds__(256) void kInitF(float* z, u32* cnt, float* psum){
  int i = blockIdx.x*256 + threadIdx.x;
  if (i < 8192) z[i] = 0.f;
  if (i < 4){ cnt[i] = 0u; psum[i] = 0.f; }
}

__global__ __launch_bounds__(256) void kFusedF(
    const float* __restrict__ x,
    const float* __restrict__ w1, const float* __restrict__ b1,
    const float* __restrict__ w2, const float* __restrict__ b2,
    const float* __restrict__ gw, const float* __restrict__ gb,
    const float* __restrict__ e1, const float* __restrict__ eb1,
    const float* __restrict__ e2, const float* __restrict__ eb2,
    float* __restrict__ z, u32* __restrict__ cnt, float* __restrict__ psum)
{
  __shared__ float xs[4][192];
  __shared__ float h1s[4][64];
  __shared__ float hs[4][64];
  __shared__ float hid[4][256];
  __shared__ float lg[4][4];
  __shared__ int   be_s[4];
  __shared__ float gv_s[4];
  __shared__ float lgp[4];
  __shared__ u32   lgc[4];
  const int tid  = threadIdx.x;
  const int w    = tid >> 6, lane = tid & 63;
  const int tok  = blockIdx.x*4 + w;
  if (tid < 4){ lgp[tid] = 0.f; lgc[tid] = 0u; }
  for (int r = 0; r < 3; ++r)
    xs[w][lane + 64*r] = x[(size_t)tok*192 + lane + 64*r];
  __syncthreads();
  float a = b1[lane];
  for (int k = 0; k < 192; ++k) a += xs[w][k]*w1[k*64 + lane];
  h1s[w][lane] = geluf(a);
  __syncthreads();
  float h = b2[lane];
  for (int k = 0; k < 64; ++k) h += h1s[w][k]*w2[k*64 + lane];
  hs[w][lane] = h;
  __syncthreads();
  if (lane < 4){
    float l = gb[lane];
    for (int k = 0; k < 64; ++k) l += hs[w][k]*gw[k*4 + lane];
    lg[w][lane] = l;
  }
  __syncthreads();
  if (lane == 0){
    float l0=lg[w][0], l1=lg[w][1], l2=lg[w][2], l3=lg[w][3];
    float mx = fmaxf(fmaxf(l0,l1),fmaxf(l2,l3));
    float x0=expf(l0-mx), x1=expf(l1-mx), x2=expf(l2-mx), x3=expf(l3-mx);
    float inv = 1.f/(x0+x1+x2+x3);
    float p0=x0*inv, p1=x1*inv, p2=x2*inv, p3=x3*inv;
    int be=0; float bv=l0;
    if (l1>bv){bv=l1;be=1;}
    if (l2>bv){bv=l2;be=2;}
    if (l3>bv){bv=l3;be=3;}
    be_s[w]=be;
    gv_s[w]=(be==0)?p0:(be==1)?p1:(be==2)?p2:p3;
    atomicAdd(&lgp[0],p0); atomicAdd(&lgp[1],p1);
    atomicAdd(&lgp[2],p2); atomicAdd(&lgp[3],p3);
    atomicAdd(&lgc[be],1u);
  }
  __syncthreads();
  const int e    = be_s[w];
  const float gv = gv_s[w];
  const float* W1 = e1 + e*16384;
  const float* W2 = e2 + e*16384;
  for (int q = 0; q < 4; ++q){
    int j = q*64 + lane;
    float s = eb1[e*256 + j];
    for (int k = 0; k < 64; ++k) s += hs[w][k]*W1[k*256 + j];
    hid[w][j] = geluf(s);
  }
  __syncthreads();
  float o = eb2[e*64 + lane];
  for (int j = 0; j < 256; ++j) o += hid[w][j]*W2[j*64 + lane];
  int b = tok >> 10;
  atomicAdd(&z[b*64 + lane], o*gv);
  __syncthreads();
  if (tid < 4){ atomicAdd(&cnt[tid], lgc[tid]); atomicAdd(&psum[tid], lgp[tid]); }
}

// ======================================================================================
extern "C" void kernel_launch(void* const* d_in, const int* in_sizes, int n_in,
                              void* d_out, int out_size, void* d_ws, size_t ws_size,
                              hipStream_t stream)
{
  const float* x    = (const float*)d_in[0];
  const float* pw1  = (const float*)d_in[1];
  const float* pb1  = (const float*)d_in[2];
  const float* pw2  = (const float*)d_in[3];
  const float* pb2  = (const float*)d_in[4];
  const float* gw   = (const float*)d_in[5];
  const float* gb   = (const float*)d_in[6];
  const float* ew1  = (const float*)d_in[7];
  const float* eb1  = (const float*)d_in[8];
  const float* ew2  = (const float*)d_in[9];
  const float* eb2  = (const float*)d_in[10];
  const float* lng  = (const float*)d_in[11];
  const float* lnb  = (const float*)d_in[12];
  const float* cw1  = (const float*)d_in[13];
  const float* cb1  = (const float*)d_in[14];
  const float* cw2  = (const float*)d_in[15];
  const float* cb2  = (const float*)d_in[16];
  char* ws  = (char*)d_ws;
  float* out = (float*)d_out;

  if (ws_size >= FAST_WS_BYTES){
    u16*  w1p  = (u16*)(ws + W1P_OFF);
    u16*  w2p  = (u16*)(ws + W2P_OFF);
    u16*  gwp  = (u16*)(ws + GWP_OFF);
    u16*  e1p  = (u16*)(ws + E1P_OFF);
    u16*  e2p  = (u16*)(ws + E2P_OFF);
    float* z    = (float*)(ws + ZF_OFF);
    u32*  cnt  = (u32*)(ws + CNTF_OFF);
    float* psum = (float*)(ws + PSUMF_OFF);
    k0_pack<<<613, 256, 0, stream>>>(pw1, pw2, gw, ew1, ew2,
                                     w1p, w2p, gwp, e1p, e2p, z, cnt, psum);
    kMain <<<2048, 256, 0, stream>>>(x, pb1, pb2, gb, w1p, w2p, gwp, e1p, e2p,
                                     eb1, eb2, z, cnt, psum);
    kFinal<<<128, 64, 0, stream>>>(z, cnt, psum, lng, lnb, cw1, cb1, cw2, cb2, out);
  } else {
    float* z    = (float*)(ws + Z_OFF);
    u32*   cnt  = (u32*)(ws + CNT_OFF);
    float* psum = (float*)(ws + PSUM_OFF);
    kInitF <<<32,    256, 0, stream>>>(z, cnt, psum);
    kFusedF<<<32768, 256, 0, stream>>>(x, pw1, pb1, pw2, pb2, gw, gb,
                                       ew1, eb1, ew2, eb2, z, cnt, psum);
    kFinal <<<128,   64,  0, stream>>>(z, cnt, psum, lng, lnb, cw1, cb1, cw2, cb2, out);
  }
}